// Round 3
// baseline (261.802 us; speedup 1.0000x reference)
//
#include <hip/hip_runtime.h>
#include <hip/hip_fp16.h>
#include <math.h>

typedef _Float16 f16;
typedef _Float16 f16x8 __attribute__((ext_vector_type(8)));
typedef float f32x4 __attribute__((ext_vector_type(4)));

#define MFMA16(a, b, c) __builtin_amdgcn_mfma_f32_16x16x32_f16((a), (b), (c), 0, 0, 0)

static constexpr float SW_W   = 1024.f;               // weight scale (exact pow2)
static constexpr float SA_A   = 64.f;                 // main-loop activation scale
static constexpr float SA1_s  = 16.f;                 // x1 activation scale
static constexpr float INV_SW    = 1.f / 1024.f;
static constexpr float INV_SASW  = 1.f / (64.f * 1024.f);
static constexpr float INV_SA1SW = 1.f / (16.f * 1024.f);

// workspace layout (bytes)
static constexpr size_t OFF_CY = 0;                                 // 128*128 f32
static constexpr size_t OFF_CX = OFF_CY + 128 * 128 * 4;
static constexpr size_t OFF_LW = OFF_CX + 128 * 128 * 4;            // 16*256 f16 (padded last1_w * SW)
static constexpr size_t OFF_XT = OFF_LW + 16 * 256 * 2;             // 8*256*1024 f16  x transposed
static constexpr size_t OFF_X1 = OFF_XT + (size_t)8 * 256 * 1024 * 2; // 8*1028*256 f16 (x1 * SA1)
static constexpr size_t OFF_W  = OFF_X1 + (size_t)8 * 1028 * 256 * 2; // 8*1028*256 f32
static constexpr size_t OFF_AY = OFF_W  + (size_t)8 * 1028 * 256 * 4; // 8*128*256 f32 (SA*(Cy@w1_top+b1))
static constexpr size_t OFF_BX = OFF_AY + (size_t)8 * 128 * 256 * 4;  // 8*128*256 f32 (SA*(Cx@w1_bot))
static constexpr size_t OFF_WT = OFF_BX + (size_t)8 * 128 * 256 * 4;  // 8*3*256*256 f16 (wj^T * SW)

static __device__ inline f32x4 zero4() { f32x4 v = {0.f, 0.f, 0.f, 0.f}; return v; }

// ---------------- positional-encoding tables + padded last1_w ----------------
__global__ void k_tables(float* __restrict__ cy, float* __restrict__ cx,
                         f16* __restrict__ lwf, const float* __restrict__ lw)
{
    int id = blockIdx.x * 256 + threadIdx.x;
    const float r = 1.99999f / 256.f;
    if (id < 32768) {
        float* dst = (id < 16384) ? cy : cx;
        int e = id & 16383;
        int row = e >> 7, f = e & 127;
        float s = -0.99999f + r + 2.f * r * (float)row;
        float coef = 6.283185307179586f * powf(10.f, (float)(f & 63) * (1.f / 64.f));
        float arg = coef * s;
        dst[e] = (f < 64) ? cosf(arg) : sinf(arg);
    } else if (id < 36864) {
        int e = id - 32768;
        int c = e >> 8, k = e & 255;
        lwf[e] = (c < 3) ? (f16)(lw[c * 256 + k] * SW_W) : (f16)0.f;
    }
}

// ---------------- x (b,c,hw) -> xT (b,hw,c) f16 ----------------
__global__ void k_transpose_x(const float* __restrict__ x, f16* __restrict__ xT)
{
    __shared__ float tile[64][65];
    const int id = blockIdx.x;
    const int b = id >> 6;
    const int ct = (id >> 2) & 15;
    const int nt = id & 3;
    const int c0 = ct << 6, n0 = nt << 6;
    const int t = threadIdx.x;
    for (int i = 0; i < 16; i++) {
        int e = i * 256 + t;
        int cc = e >> 6, nn = e & 63;
        tile[cc][nn] = x[(size_t)((b << 10) + c0 + cc) * 256 + n0 + nn];
    }
    __syncthreads();
    for (int i = 0; i < 16; i++) {
        int e = i * 256 + t;
        int nn = e >> 6, cc = e & 63;
        xT[(size_t)((b << 8) + n0 + nn) * 1024 + c0 + cc] = (f16)tile[cc][nn];
    }
}

// ---------------- generic 64xK -> 64x256 f16 MFMA GEMM ----------------
// MODE 0: x1 = conv_w @ x      (A=conv_w f32 *SW, B=xT f16, K=1024) -> x1 f16 (*SA1, +conv_b)
// MODE 1: W  = x1 @ wfine^T    (A=x1 f16 (SA1), B=wfine f32 *SW, K=256) -> W f32 (+wfine_b)
template <int MODE>
__global__ __launch_bounds__(256, 2) void k_gemm(
    const float* __restrict__ Af32, const f16* __restrict__ Af16,
    const f16* __restrict__ Bf16, const float* __restrict__ Bf32,
    f16* __restrict__ out16, float* __restrict__ outW,
    const float* __restrict__ bias)
{
    constexpr int NC = MODE ? 8 : 32;
    __shared__ __align__(16) f16 Ab[2][64 * 32];
    __shared__ __align__(16) f16 Bb[2][256 * 32];
    const int t = threadIdx.x;
    const int lane = t & 63;
    const int wc = t >> 6;                 // wave = 64-col slice
    const int nlo = lane & 15, q4 = lane >> 4;
    const int blk = blockIdx.x;
    const int b = blk / 17, mtile = blk % 17;
    const int m0 = mtile << 6;

    auto stageA = [&](int buf, int k0) {
        const int r = t >> 2, q = t & 3;
        const int m = m0 + r;
        f16x8 v;
        if (m < 1028) {
            if constexpr (MODE == 0) {
                const float* src = Af32 + (size_t)m * 1024 + k0 + (q << 3);
                #pragma unroll
                for (int i = 0; i < 8; i++) v[i] = (f16)(src[i] * SW_W);
            } else {
                v = *(const f16x8*)(Af16 + (size_t)(b * 1028 + m) * 256 + k0 + (q << 3));
            }
        } else {
            #pragma unroll
            for (int i = 0; i < 8; i++) v[i] = (f16)0.f;
        }
        *(f16x8*)(&Ab[buf][(r << 5) + (q << 3)]) = v;
    };
    auto stageB = [&](int buf, int k0) {
        if constexpr (MODE == 0) {
            const f16* src = Bf16 + (size_t)((b << 8) + t) * 1024 + k0;
            #pragma unroll
            for (int i = 0; i < 4; i++)
                *(f16x8*)(&Bb[buf][(t << 5) + (i << 3)]) = *(const f16x8*)(src + (i << 3));
        } else {
            const float* src = Bf32 + (t << 8) + k0;
            #pragma unroll
            for (int i = 0; i < 4; i++) {
                f16x8 v;
                #pragma unroll
                for (int j = 0; j < 8; j++) v[j] = (f16)(src[(i << 3) + j] * SW_W);
                *(f16x8*)(&Bb[buf][(t << 5) + (i << 3)]) = v;
            }
        }
    };

    f32x4 acc[4][4];
    #pragma unroll
    for (int mt = 0; mt < 4; mt++)
        #pragma unroll
        for (int nt = 0; nt < 4; nt++) acc[mt][nt] = zero4();

    stageA(0, 0); stageB(0, 0);
    __syncthreads();
    for (int c = 0; c < NC; c++) {
        const int cb = c & 1;
        if (c + 1 < NC) { stageA(cb ^ 1, (c + 1) << 5); stageB(cb ^ 1, (c + 1) << 5); }
        f16x8 af[4], bf[4];
        #pragma unroll
        for (int mt = 0; mt < 4; mt++)
            af[mt] = *(const f16x8*)(&Ab[cb][(((mt << 4) + nlo) << 5) + (q4 << 3)]);
        #pragma unroll
        for (int nt = 0; nt < 4; nt++)
            bf[nt] = *(const f16x8*)(&Bb[cb][((((wc << 2) + nt) << 4) + nlo) * 32 + (q4 << 3)]);
        #pragma unroll
        for (int mt = 0; mt < 4; mt++)
            #pragma unroll
            for (int nt = 0; nt < 4; nt++)
                acc[mt][nt] = MFMA16(af[mt], bf[nt], acc[mt][nt]);
        __syncthreads();
    }
    #pragma unroll
    for (int nt = 0; nt < 4; nt++) {
        const int nn = (((wc << 2) + nt) << 4) + nlo;
        #pragma unroll
        for (int mt = 0; mt < 4; mt++) {
            #pragma unroll
            for (int i = 0; i < 4; i++) {
                const int m = m0 + (mt << 4) + (q4 << 2) + i;
                if (m < 1028) {
                    if constexpr (MODE == 0) {
                        float v = (acc[mt][nt][i] * INV_SW + bias[m]) * SA1_s;
                        out16[(size_t)(b * 1028 + m) * 256 + nn] = (f16)v;
                    } else {
                        outW[(size_t)(b * 1028 + m) * 256 + nn] =
                            acc[mt][nt][i] * INV_SA1SW + bias[nn];
                    }
                }
            }
        }
    }
}

// ---------------- separable layer-1: AyS = SA*(Cy@w1_top + b1), BxS = SA*(Cx@w1_bot) ----------------
__global__ void k_axby(const float* __restrict__ cy, const float* __restrict__ cx,
                       const float* __restrict__ W, float* __restrict__ ay,
                       float* __restrict__ bx)
{
    const int id = blockIdx.x;                 // 64 = 8b * 2which * 4 row-tiles
    const int b = id >> 3, which = (id >> 2) & 1, rtile = id & 3;
    const int r0 = rtile << 5;
    const int t = threadIdx.x;                 // n = feature col
    const float* ctab = which ? cx : cy;
    const float* Wb = W + (size_t)(b * 1028 + (which ? 128 : 0)) * 256;
    float acc[32];
    #pragma unroll
    for (int r = 0; r < 32; r++) acc[r] = 0.f;
    for (int k = 0; k < 128; k++) {
        const float wv = Wb[(k << 8) + t];
        #pragma unroll
        for (int r = 0; r < 32; r++)
            acc[r] = fmaf(ctab[((r0 + r) << 7) + k], wv, acc[r]);
    }
    const float b1v = which ? 0.f : W[(size_t)(b * 1028 + 256) * 256 + t];
    float* dst = which ? bx : ay;
    for (int r = 0; r < 32; r++)
        dst[(size_t)((b << 7) + r0 + r) * 256 + t] = (acc[r] + b1v) * SA_A;
}

// ---------------- W slices -> wjT f16 (transposed, *SW) ----------------
__global__ void k_castw(const float* __restrict__ W, f16* __restrict__ wjT)
{
    __shared__ float tile[64][65];
    const int id = blockIdx.x;                  // 384 = 8b * 3jj * 16 tiles
    const int b = id / 48;
    const int rr = id % 48;
    const int jj = rr / 16;
    const int tt = rr % 16;
    const int k0 = (tt >> 2) << 6, n0 = (tt & 3) << 6;
    const int t = threadIdx.x;
    const float* src = W + (size_t)(b * 1028 + 257 * (jj + 1)) * 256;
    for (int i = 0; i < 16; i++) {
        int e = i * 256 + t;
        int kk = e >> 6, nn = e & 63;
        tile[kk][nn] = src[((k0 + kk) << 8) + n0 + nn];
    }
    __syncthreads();
    f16* dst = wjT + (size_t)(b * 3 + jj) * 65536;
    for (int i = 0; i < 16; i++) {
        int e = i * 256 + t;
        int nn = e >> 6, kk = e & 63;
        dst[((n0 + nn) << 8) + k0 + kk] = (f16)(tile[kk][nn] * SW_W);
    }
}

// ---------------- fused MLP: layers 2..4 + final projection + silu ----------------
__global__ __launch_bounds__(256, 2) void k_main(
    const f16* __restrict__ wjT, const float* __restrict__ Wfull,
    const float* __restrict__ ayS, const float* __restrict__ bxS,
    const f16* __restrict__ lwf, const float* __restrict__ lb,
    const float* __restrict__ pa_p, float* __restrict__ out)
{
    __shared__ __align__(16) unsigned char actS[32768];     // 64 rows x 256 f16, slot-swizzled
    __shared__ __align__(16) unsigned char wS[2][16384];    // wj chunk: [256 n][32 k] f16
    const int t = threadIdx.x;
    const int lane = t & 63;
    const int wc = t >> 6;                     // wave = 64-col slice
    const int nlo = lane & 15, q4 = lane >> 4;
    const int blk = blockIdx.x;
    const int b = blk >> 8, rt = blk & 255;
    const int p0 = rt << 6;
    const int y = p0 >> 7, x0 = p0 & 127;
    const float pa = pa_p[0];

    // ---- init act = f16(prelu(AyS[y] + BxS[x])) ----
    {
        const int r = t & 63, g = t >> 6;
        const float* ayr = ayS + (size_t)((b << 7) + y) * 256;
        const float* bxr = bxS + (size_t)((b << 7) + x0 + r) * 256;
        const int rx = r & 7;
        #pragma unroll
        for (int mm = 0; mm < 8; mm++) {
            const int slot = (g << 3) + mm;
            const int f0 = slot << 3;
            f16x8 v;
            #pragma unroll
            for (int i = 0; i < 8; i++) {
                float hv = ayr[f0 + i] + bxr[f0 + i];
                hv = fmaxf(hv, 0.f) + pa * fminf(hv, 0.f);
                v[i] = (f16)hv;
            }
            *(f16x8*)(actS + (r << 9) + ((slot ^ rx) << 4)) = v;
        }
    }

    auto stage_w = [&](int buf, int jj, int c) {
        const f16* src = wjT + (size_t)((b * 3 + jj) * 256 + t) * 256 + (c << 5);
        f16* d = (f16*)(wS[buf]) + (t << 5);
        #pragma unroll
        for (int i = 0; i < 4; i++)
            *(f16x8*)(d + (i << 3)) = *(const f16x8*)(src + (i << 3));
    };
    auto stage_lw = [&]() {
        #pragma unroll
        for (int dd = 0; dd < 2; dd++) {
            const int sid = (t << 1) + dd;
            const int cc = sid >> 5, ss = sid & 31;
            *(f16x8*)(wS[0] + (cc << 9) + ((ss ^ (cc & 7)) << 4)) =
                *(const f16x8*)(lwf + (cc << 8) + (ss << 3));
        }
    };

    stage_w(0, 0, 0);
    __syncthreads();

    for (int jj = 0; jj < 3; jj++) {
        f32x4 acc[4][4];
        #pragma unroll
        for (int mt = 0; mt < 4; mt++)
            #pragma unroll
            for (int nt = 0; nt < 4; nt++) acc[mt][nt] = zero4();

        for (int c = 0; c < 8; c++) {
            const int cb = c & 1;
            if (c < 7)       stage_w(cb ^ 1, jj, c + 1);
            else if (jj < 2) stage_w(cb ^ 1, jj + 1, 0);
            else             stage_lw();
            const int sl = (c << 2) + q4;
            f16x8 af[4], bf[4];
            #pragma unroll
            for (int mt = 0; mt < 4; mt++) {
                const int rr = (mt << 4) + nlo;
                af[mt] = *(const f16x8*)(actS + (rr << 9) + ((sl ^ (rr & 7)) << 4));
            }
            #pragma unroll
            for (int nt = 0; nt < 4; nt++) {
                const int brow = (((wc << 2) + nt) << 4) + nlo;
                bf[nt] = *(const f16x8*)(wS[cb] + (brow << 6) + (q4 << 4));
            }
            #pragma unroll
            for (int mt = 0; mt < 4; mt++)
                #pragma unroll
                for (int nt = 0; nt < 4; nt++)
                    acc[mt][nt] = MFMA16(af[mt], bf[nt], acc[mt][nt]);
            __syncthreads();
        }

        // epilogue: act <- f16(prelu(acc/SW + SA*b_j))  (prelu is pos-homogeneous)
        const float* bias = Wfull + (size_t)(b * 1028 + 257 * (jj + 1) + 256) * 256;
        #pragma unroll
        for (int nt = 0; nt < 4; nt++) {
            const int nn = (((wc << 2) + nt) << 4) + nlo;
            const float bs = bias[nn] * SA_A;
            const int slot = nn >> 3;
            #pragma unroll
            for (int mt = 0; mt < 4; mt++) {
                #pragma unroll
                for (int i = 0; i < 4; i++) {
                    const int rr = (mt << 4) + (q4 << 2) + i;
                    float v = acc[mt][nt][i] * INV_SW + bs;
                    v = fmaxf(v, 0.f) + pa * fminf(v, 0.f);
                    *(f16*)(actS + (rr << 9) + ((slot ^ (rr & 7)) << 4) + ((nn & 7) << 1)) = (f16)v;
                }
            }
        }
        __syncthreads();   // cross-wave: next layer reads cols written by other waves
    }

    // ---- final 256->3 projection + silu (wave 0 only) ----
    if (wc == 0) {
        f32x4 acc2[4];
        #pragma unroll
        for (int mt = 0; mt < 4; mt++) acc2[mt] = zero4();
        for (int c = 0; c < 8; c++) {
            const int sl = (c << 2) + q4;
            const f16x8 lf = *(const f16x8*)(wS[0] + (nlo << 9) + ((sl ^ (nlo & 7)) << 4));
            #pragma unroll
            for (int mt = 0; mt < 4; mt++) {
                const int rr = (mt << 4) + nlo;
                const f16x8 af = *(const f16x8*)(actS + (rr << 9) + ((sl ^ (rr & 7)) << 4));
                acc2[mt] = MFMA16(af, lf, acc2[mt]);
            }
        }
        if (nlo < 3) {
            const float lbv = lb[nlo];
            #pragma unroll
            for (int mt = 0; mt < 4; mt++) {
                float* ob = out + ((size_t)(b * 3 + nlo) << 14) + p0 + (mt << 4) + (q4 << 2);
                #pragma unroll
                for (int i = 0; i < 4; i++) {
                    float z = acc2[mt][i] * INV_SASW + lbv;
                    ob[i] = z / (1.f + expf(-z));
                }
            }
        }
    }
}

extern "C" void kernel_launch(void* const* d_in, const int* in_sizes, int n_in,
                              void* d_out, int out_size, void* d_ws, size_t ws_size,
                              hipStream_t stream)
{
    (void)in_sizes; (void)n_in; (void)out_size; (void)ws_size;
    const float* x       = (const float*)d_in[0];
    const float* conv_w  = (const float*)d_in[1];
    const float* conv_b  = (const float*)d_in[2];
    const float* wfine_w = (const float*)d_in[3];
    const float* wfine_b = (const float*)d_in[4];
    const float* last1_w = (const float*)d_in[5];
    const float* last1_b = (const float*)d_in[6];
    const float* prelu_a = (const float*)d_in[7];
    char* ws = (char*)d_ws;
    float* Cy  = (float*)(ws + OFF_CY);
    float* Cx  = (float*)(ws + OFF_CX);
    f16*   lwf = (f16*)(ws + OFF_LW);
    f16*   xT  = (f16*)(ws + OFF_XT);
    f16*   x1  = (f16*)(ws + OFF_X1);
    float* W   = (float*)(ws + OFF_W);
    float* AyS = (float*)(ws + OFF_AY);
    float* BxS = (float*)(ws + OFF_BX);
    f16*   wjT = (f16*)(ws + OFF_WT);

    k_tables<<<144, 256, 0, stream>>>(Cy, Cx, lwf, last1_w);
    k_transpose_x<<<512, 256, 0, stream>>>(x, xT);
    k_gemm<0><<<136, 256, 0, stream>>>(conv_w, nullptr, xT, nullptr, x1, nullptr, conv_b);
    k_gemm<1><<<136, 256, 0, stream>>>(nullptr, x1, nullptr, wfine_w, nullptr, W, wfine_b);
    k_axby<<<64, 256, 0, stream>>>(Cy, Cx, W, AyS, BxS);
    k_castw<<<384, 256, 0, stream>>>(W, wjT);
    k_main<<<2048, 256, 0, stream>>>(wjT, W, AyS, BxS, lwf, last1_b, prelu_a, (float*)d_out);
}

// Round 4
// 154.330 us; speedup vs baseline: 1.6964x; 1.6964x over previous
//
#include <hip/hip_runtime.h>
#include <hip/hip_fp16.h>
#include <math.h>

typedef _Float16 f16;
typedef _Float16 f16x8 __attribute__((ext_vector_type(8)));
typedef float f32x4 __attribute__((ext_vector_type(4)));

#define MFMA16(a, b, c) __builtin_amdgcn_mfma_f32_16x16x32_f16((a), (b), (c), 0, 0, 0)

static constexpr float SW_W   = 1024.f;               // weight scale (exact pow2)
static constexpr float SA_A   = 64.f;                 // main-loop activation scale
static constexpr float SA1_s  = 16.f;                 // x1 activation scale
static constexpr float INV_SW    = 1.f / 1024.f;
static constexpr float INV_SASW  = 1.f / (64.f * 1024.f);
static constexpr float INV_SA1SW = 1.f / (16.f * 1024.f);

// workspace layout (bytes)
static constexpr size_t OFF_CY = 0;                                   // 128*128 f32
static constexpr size_t OFF_CX = OFF_CY + 128 * 128 * 4;
static constexpr size_t OFF_LW = OFF_CX + 128 * 128 * 4;              // 16*256 f16 (padded last1_w * SW)
static constexpr size_t OFF_XT = OFF_LW + 16 * 256 * 2;               // 8*256*1024 f16  x transposed
static constexpr size_t OFF_X1 = OFF_XT + (size_t)8 * 256 * 1024 * 2; // 8*1028*256 f16 (x1 * SA1)
static constexpr size_t OFF_W  = OFF_X1 + (size_t)8 * 1028 * 256 * 2; // 8*1028*256 f32
static constexpr size_t OFF_AY = OFF_W  + (size_t)8 * 1028 * 256 * 4; // 8*128*256 f16 (SA*(Cy@w1_top+b1))
static constexpr size_t OFF_BX = OFF_AY + (size_t)8 * 128 * 256 * 2;  // 8*128*256 f16 (SA*(Cx@w1_bot))
static constexpr size_t OFF_WT = OFF_BX + (size_t)8 * 128 * 256 * 2;  // 8*3*256*256 f16 (wj^T * SW)

static __device__ inline f32x4 zero4() { f32x4 v = {0.f, 0.f, 0.f, 0.f}; return v; }

// ---------------- positional-encoding tables + padded last1_w ----------------
__global__ void k_tables(float* __restrict__ cy, float* __restrict__ cx,
                         f16* __restrict__ lwf, const float* __restrict__ lw)
{
    int id = blockIdx.x * 256 + threadIdx.x;
    const float r = 1.99999f / 256.f;
    if (id < 32768) {
        float* dst = (id < 16384) ? cy : cx;
        int e = id & 16383;
        int row = e >> 7, f = e & 127;
        float s = -0.99999f + r + 2.f * r * (float)row;
        float coef = 6.283185307179586f * powf(10.f, (float)(f & 63) * (1.f / 64.f));
        float arg = coef * s;
        dst[e] = (f < 64) ? cosf(arg) : sinf(arg);
    } else if (id < 36864) {
        int e = id - 32768;
        int c = e >> 8, k = e & 255;
        lwf[e] = (c < 3) ? (f16)(lw[c * 256 + k] * SW_W) : (f16)0.f;
    }
}

// ---------------- x (b,c,hw) -> xT (b,hw,c) f16 ----------------
__global__ void k_transpose_x(const float* __restrict__ x, f16* __restrict__ xT)
{
    __shared__ float tile[64][65];
    const int id = blockIdx.x;
    const int b = id >> 6;
    const int ct = (id >> 2) & 15;
    const int nt = id & 3;
    const int c0 = ct << 6, n0 = nt << 6;
    const int t = threadIdx.x;
    for (int i = 0; i < 16; i++) {
        int e = i * 256 + t;
        int cc = e >> 6, nn = e & 63;
        tile[cc][nn] = x[(size_t)((b << 10) + c0 + cc) * 256 + n0 + nn];
    }
    __syncthreads();
    for (int i = 0; i < 16; i++) {
        int e = i * 256 + t;
        int nn = e >> 6, cc = e & 63;
        xT[(size_t)((b << 8) + n0 + nn) * 1024 + c0 + cc] = (f16)tile[cc][nn];
    }
}

// ---------------- 64x64-tile MFMA GEMM ----------------
// MODE 0: x1 = conv_w @ x   (A=conv_w f32 *SW, B=xT f16, K=1024) -> x1 f16 (*SA1, +conv_b)
// MODE 1: W  = x1 @ wfine^T (A=x1 f16, B=wfine f32 *SW, K=256)   -> W f32 (+wfine_b)
// Staging: wave-instr writes 64 consecutive 16B slots (conflict-free).
// LDS tile layout: [64 rows][32 k] f16, slot t <-> (row=t>>2, k8=t&3).
template <int MODE>
__global__ __launch_bounds__(256, 4) void k_gemm(
    const float* __restrict__ Af32, const f16* __restrict__ Af16,
    const f16* __restrict__ Bf16, const float* __restrict__ Bf32,
    f16* __restrict__ out16, float* __restrict__ outW,
    const float* __restrict__ bias)
{
    constexpr int NC = MODE ? 8 : 32;
    __shared__ __align__(16) f16 Ab[2][64 * 32];
    __shared__ __align__(16) f16 Bb[2][64 * 32];
    const int t = threadIdx.x;
    const int lane = t & 63;
    const int wc = t >> 6;                 // wave = 16-col slice
    const int nlo = lane & 15, q4 = lane >> 4;
    const int blk = blockIdx.x;
    const int b = blk / 68;
    const int rem = blk % 68;
    const int m0 = (rem >> 2) << 6;
    const int n0 = (rem & 3) << 6;
    const int srow = t >> 2, sk = (t & 3) << 3;   // staged (row, k-offset)

    auto stageA = [&](int buf, int k0) {
        const int m = m0 + srow;
        f16x8 v;
        if (m < 1028) {
            if constexpr (MODE == 0) {
                const float* src = Af32 + (size_t)m * 1024 + k0 + sk;
                #pragma unroll
                for (int i = 0; i < 8; i++) v[i] = (f16)(src[i] * SW_W);
            } else {
                v = *(const f16x8*)(Af16 + (size_t)(b * 1028 + m) * 256 + k0 + sk);
            }
        } else {
            #pragma unroll
            for (int i = 0; i < 8; i++) v[i] = (f16)0.f;
        }
        *(f16x8*)(&Ab[buf][t << 3]) = v;
    };
    auto stageB = [&](int buf, int k0) {
        const int n = n0 + srow;
        f16x8 v;
        if constexpr (MODE == 0) {
            v = *(const f16x8*)(Bf16 + (size_t)((b << 8) + n) * 1024 + k0 + sk);
        } else {
            const float* src = Bf32 + (size_t)n * 256 + k0 + sk;
            #pragma unroll
            for (int i = 0; i < 8; i++) v[i] = (f16)(src[i] * SW_W);
        }
        *(f16x8*)(&Bb[buf][t << 3]) = v;
    };

    f32x4 acc[4];
    #pragma unroll
    for (int mt = 0; mt < 4; mt++) acc[mt] = zero4();

    stageA(0, 0); stageB(0, 0);
    __syncthreads();
    for (int c = 0; c < NC; c++) {
        const int cb = c & 1;
        if (c + 1 < NC) { stageA(cb ^ 1, (c + 1) << 5); stageB(cb ^ 1, (c + 1) << 5); }
        f16x8 af[4], bf;
        bf = *(const f16x8*)(&Bb[cb][(((wc << 4) + nlo) << 5) + (q4 << 3)]);
        #pragma unroll
        for (int mt = 0; mt < 4; mt++)
            af[mt] = *(const f16x8*)(&Ab[cb][(((mt << 4) + nlo) << 5) + (q4 << 3)]);
        #pragma unroll
        for (int mt = 0; mt < 4; mt++)
            acc[mt] = MFMA16(af[mt], bf, acc[mt]);
        __syncthreads();
    }
    const int nn = n0 + (wc << 4) + nlo;
    #pragma unroll
    for (int mt = 0; mt < 4; mt++) {
        #pragma unroll
        for (int i = 0; i < 4; i++) {
            const int m = m0 + (mt << 4) + (q4 << 2) + i;
            if (m < 1028) {
                if constexpr (MODE == 0) {
                    float v = (acc[mt][i] * INV_SW + bias[m]) * SA1_s;
                    out16[(size_t)(b * 1028 + m) * 256 + nn] = (f16)v;
                } else {
                    outW[(size_t)(b * 1028 + m) * 256 + nn] =
                        acc[mt][i] * INV_SA1SW + bias[nn];
                }
            }
        }
    }
}

// ---------------- separable layer-1 (f16 out): ayF = SA*(Cy@w1_top + b1), bxF = SA*(Cx@w1_bot) ----------------
__global__ void k_axby(const float* __restrict__ cy, const float* __restrict__ cx,
                       const float* __restrict__ W, f16* __restrict__ ayF,
                       f16* __restrict__ bxF)
{
    const int id = blockIdx.x;                 // 256 = 8b * 2which * 16 row-tiles
    const int b = id >> 5, which = (id >> 4) & 1, rtile = id & 15;
    const int r0 = rtile << 3;
    const int t = threadIdx.x;                 // n = feature col
    const float* ctab = which ? cx : cy;
    const float* Wb = W + (size_t)(b * 1028 + (which ? 128 : 0)) * 256;
    float acc[8];
    #pragma unroll
    for (int r = 0; r < 8; r++) acc[r] = 0.f;
    for (int k = 0; k < 128; k++) {
        const float wv = Wb[(k << 8) + t];
        #pragma unroll
        for (int r = 0; r < 8; r++)
            acc[r] = fmaf(ctab[((r0 + r) << 7) + k], wv, acc[r]);
    }
    const float b1v = which ? 0.f : W[(size_t)(b * 1028 + 256) * 256 + t];
    f16* dst = which ? bxF : ayF;
    for (int r = 0; r < 8; r++)
        dst[(size_t)((b << 7) + r0 + r) * 256 + t] = (f16)((acc[r] + b1v) * SA_A);
}

// ---------------- W slices -> wjT f16 (transposed, *SW) ----------------
__global__ void k_castw(const float* __restrict__ W, f16* __restrict__ wjT)
{
    __shared__ float tile[64][65];
    const int id = blockIdx.x;                  // 384 = 8b * 3jj * 16 tiles
    const int b = id / 48;
    const int rr = id % 48;
    const int jj = rr / 16;
    const int tt = rr % 16;
    const int k0 = (tt >> 2) << 6, n0 = (tt & 3) << 6;
    const int t = threadIdx.x;
    const float* src = W + (size_t)(b * 1028 + 257 * (jj + 1)) * 256;
    for (int i = 0; i < 16; i++) {
        int e = i * 256 + t;
        int kk = e >> 6, nn = e & 63;
        tile[kk][nn] = src[((k0 + kk) << 8) + n0 + nn];
    }
    __syncthreads();
    f16* dst = wjT + (size_t)(b * 3 + jj) * 65536;
    for (int i = 0; i < 16; i++) {
        int e = i * 256 + t;
        int nn = e >> 6, kk = e & 63;
        dst[((n0 + nn) << 8) + k0 + kk] = (f16)(tile[kk][nn] * SW_W);
    }
}

// ---------------- fused MLP: layers 2..4 + final projection + silu ----------------
// act: 64px x 256f f16 in LDS, slot-swizzled. wj streamed in k=32 chunks through
// double-buffered LDS via registers (global->reg issued one chunk early).
__global__ __launch_bounds__(256, 2) void k_main(
    const f16* __restrict__ wjT, const float* __restrict__ Wfull,
    const f16* __restrict__ ayF, const f16* __restrict__ bxF,
    const f16* __restrict__ lwf, const float* __restrict__ lb,
    const float* __restrict__ pa_p, float* __restrict__ out)
{
    __shared__ __align__(16) unsigned char actS[32768];     // 64 rows x 256 f16, slot-swizzled
    __shared__ __align__(16) unsigned char wS[2][16384];    // wj chunk: [256 n][32 k] f16
    const int t = threadIdx.x;
    const int lane = t & 63;
    const int wc = t >> 6;                     // wave = 64-col slice
    const int nlo = lane & 15, q4 = lane >> 4;
    const int blk = blockIdx.x;
    const int b = blk & 7, rt = blk >> 3;      // batch = low bits -> XCD-local wjT
    const int p0 = rt << 6;
    const int y = p0 >> 7, x0 = p0 & 127;
    const float pa = pa_p[0];

    const f16* wbase = wjT + (size_t)(b * 3) * 65536;
    f16x8 wreg[4];
    // load chunk g (g = jj*8+cc): rows (i*64 + t>>2), k = cc*32 + (t&3)*8
    auto issue_load = [&](int g) {
        const f16* src = wbase + (g >> 3) * 65536 + (t >> 2) * 256 + ((g & 7) << 5) + ((t & 3) << 3);
        #pragma unroll
        for (int i = 0; i < 4; i++)
            wreg[i] = *(const f16x8*)(src + i * 16384);
    };
    // conflict-free: wave-instr i writes 64 consecutive 16B slots
    auto write_ws = [&](int buf) {
        unsigned char* d = wS[buf] + ((t >> 2) << 6) + ((t & 3) << 4);
        #pragma unroll
        for (int i = 0; i < 4; i++)
            *(f16x8*)(d + (i << 12)) = wreg[i];
    };

    // ---- init act = f16(prelu(ayF[y] + bxF[x])) ----
    {
        const int r = t & 63, g = t >> 6;
        const f16* ayr = ayF + (size_t)((b << 7) + y) * 256;
        const f16* bxr = bxF + (size_t)((b << 7) + x0 + r) * 256;
        const int rx = r & 7;
        #pragma unroll
        for (int mm = 0; mm < 8; mm++) {
            const int slot = (g << 3) + mm;
            const int f0 = slot << 3;
            f16x8 av = *(const f16x8*)(ayr + f0);
            f16x8 bv = *(const f16x8*)(bxr + f0);
            f16x8 v;
            #pragma unroll
            for (int i = 0; i < 8; i++) {
                float hv = (float)av[i] + (float)bv[i];
                hv = fmaxf(hv, 0.f) + pa * fminf(hv, 0.f);
                v[i] = (f16)hv;
            }
            *(f16x8*)(actS + (r << 9) + ((slot ^ rx) << 4)) = v;
        }
    }

    issue_load(0);
    write_ws(0);
    issue_load(1);
    __syncthreads();

    for (int jj = 0; jj < 3; jj++) {
        f32x4 acc[4][4];
        #pragma unroll
        for (int mt = 0; mt < 4; mt++)
            #pragma unroll
            for (int nt = 0; nt < 4; nt++) acc[mt][nt] = zero4();

        for (int cc = 0; cc < 8; cc++) {
            const int g = jj * 8 + cc;
            const int cb = g & 1;
            if (g < 23) write_ws(cb ^ 1);          // chunk g+1 (waits its loads)
            if (g + 2 < 24) issue_load(g + 2);     // prefetch 2 ahead
            const int sl = (cc << 2) + q4;
            f16x8 af[4], bf[4];
            #pragma unroll
            for (int mt = 0; mt < 4; mt++) {
                const int rr = (mt << 4) + nlo;
                af[mt] = *(const f16x8*)(actS + (rr << 9) + ((sl ^ (rr & 7)) << 4));
            }
            #pragma unroll
            for (int nt = 0; nt < 4; nt++) {
                const int brow = (((wc << 2) + nt) << 4) + nlo;
                bf[nt] = *(const f16x8*)(wS[cb] + (brow << 6) + (q4 << 4));
            }
            #pragma unroll
            for (int mt = 0; mt < 4; mt++)
                #pragma unroll
                for (int nt = 0; nt < 4; nt++)
                    acc[mt][nt] = MFMA16(af[mt], bf[nt], acc[mt][nt]);
            __syncthreads();
        }

        // epilogue: act <- f16(prelu(acc/SW + SA*b_j))
        const float* bias = Wfull + (size_t)(b * 1028 + 257 * (jj + 1) + 256) * 256;
        #pragma unroll
        for (int nt = 0; nt < 4; nt++) {
            const int nn = (((wc << 2) + nt) << 4) + nlo;
            const float bs = bias[nn] * SA_A;
            const int slot = nn >> 3;
            #pragma unroll
            for (int mt = 0; mt < 4; mt++) {
                #pragma unroll
                for (int i = 0; i < 4; i++) {
                    const int rr = (mt << 4) + (q4 << 2) + i;
                    float v = acc[mt][nt][i] * INV_SW + bs;
                    v = fmaxf(v, 0.f) + pa * fminf(v, 0.f);
                    *(f16*)(actS + (rr << 9) + ((slot ^ (rr & 7)) << 4) + ((nn & 7) << 1)) = (f16)v;
                }
            }
        }
        __syncthreads();   // next layer / projection reads other waves' columns
    }

    // ---- final 256->3 projection + silu: each wave owns one 16-px tile ----
    {
        f32x4 acc2 = zero4();
        const int rr = (wc << 4) + nlo;
        for (int c = 0; c < 8; c++) {
            const int sl = (c << 2) + q4;
            const f16x8 af = *(const f16x8*)(actS + (rr << 9) + ((sl ^ (rr & 7)) << 4));
            const f16x8 lf = *(const f16x8*)(lwf + nlo * 256 + (c << 5) + (q4 << 3));
            acc2 = MFMA16(af, lf, acc2);
        }
        if (nlo < 3) {
            const float lbv = lb[nlo];
            float* ob = out + ((size_t)(b * 3 + nlo) << 14) + p0 + (wc << 4) + (q4 << 2);
            #pragma unroll
            for (int i = 0; i < 4; i++) {
                float z = acc2[i] * INV_SASW + lbv;
                ob[i] = z / (1.f + expf(-z));
            }
        }
    }
}

extern "C" void kernel_launch(void* const* d_in, const int* in_sizes, int n_in,
                              void* d_out, int out_size, void* d_ws, size_t ws_size,
                              hipStream_t stream)
{
    (void)in_sizes; (void)n_in; (void)out_size; (void)ws_size;
    const float* x       = (const float*)d_in[0];
    const float* conv_w  = (const float*)d_in[1];
    const float* conv_b  = (const float*)d_in[2];
    const float* wfine_w = (const float*)d_in[3];
    const float* wfine_b = (const float*)d_in[4];
    const float* last1_w = (const float*)d_in[5];
    const float* last1_b = (const float*)d_in[6];
    const float* prelu_a = (const float*)d_in[7];
    char* ws = (char*)d_ws;
    float* Cy  = (float*)(ws + OFF_CY);
    float* Cx  = (float*)(ws + OFF_CX);
    f16*   lwf = (f16*)(ws + OFF_LW);
    f16*   xT  = (f16*)(ws + OFF_XT);
    f16*   x1  = (f16*)(ws + OFF_X1);
    float* W   = (float*)(ws + OFF_W);
    f16*   AyF = (f16*)(ws + OFF_AY);
    f16*   BxF = (f16*)(ws + OFF_BX);
    f16*   wjT = (f16*)(ws + OFF_WT);

    k_tables<<<144, 256, 0, stream>>>(Cy, Cx, lwf, last1_w);
    k_transpose_x<<<512, 256, 0, stream>>>(x, xT);
    k_gemm<0><<<544, 256, 0, stream>>>(conv_w, nullptr, xT, nullptr, x1, nullptr, conv_b);
    k_gemm<1><<<544, 256, 0, stream>>>(nullptr, x1, nullptr, wfine_w, nullptr, W, wfine_b);
    k_axby<<<256, 256, 0, stream>>>(Cy, Cx, W, AyF, BxF);
    k_castw<<<384, 256, 0, stream>>>(W, wjT);
    k_main<<<2048, 256, 0, stream>>>(wjT, W, AyF, BxF, lwf, last1_b, prelu_a, (float*)d_out);
}

// Round 5
// 124.151 us; speedup vs baseline: 2.1087x; 1.2431x over previous
//
#include <hip/hip_runtime.h>
#include <hip/hip_fp16.h>
#include <math.h>

typedef _Float16 f16;
typedef _Float16 f16x4 __attribute__((ext_vector_type(4)));
typedef _Float16 f16x8 __attribute__((ext_vector_type(8)));
typedef float f32x4 __attribute__((ext_vector_type(4)));

#define MFMA16(a, b, c) __builtin_amdgcn_mfma_f32_16x16x32_f16((a), (b), (c), 0, 0, 0)

static constexpr float SW_W   = 1024.f;               // weight scale (exact pow2)
static constexpr float SA_A   = 64.f;                 // main-loop activation scale
static constexpr float SA1_s  = 16.f;                 // x1 activation scale
static constexpr float INV_SW    = 1.f / 1024.f;
static constexpr float INV_SASW  = 1.f / (64.f * 1024.f);
static constexpr float INV_SA1SW = 1.f / (16.f * 1024.f);

// workspace layout (bytes)
static constexpr size_t OFF_CY = 0;                                   // 128*128 f32
static constexpr size_t OFF_CX = OFF_CY + 128 * 128 * 4;
static constexpr size_t OFF_LW = OFF_CX + 128 * 128 * 4;              // 512*8 f16 fragment-ordered last1_w * SW
static constexpr size_t OFF_XT = OFF_LW + 16 * 256 * 2;               // 8*256*1024 f16  x transposed
static constexpr size_t OFF_X1 = OFF_XT + (size_t)8 * 256 * 1024 * 2; // 8*1028*256 f16 (x1 * SA1)
static constexpr size_t OFF_W  = OFF_X1 + (size_t)8 * 1028 * 256 * 2; // 8*1028*256 f32
static constexpr size_t OFF_AY = OFF_W  + (size_t)8 * 1028 * 256 * 4; // 8*128*256 f16 (SA*(Cy@w1_top+b1))
static constexpr size_t OFF_BX = OFF_AY + (size_t)8 * 128 * 256 * 2;  // 8*128*256 f16 (SA*(Cx@w1_bot))
static constexpr size_t OFF_WT = OFF_BX + (size_t)8 * 128 * 256 * 2;  // 8*3*65536 f16 (wj fragment-ordered * SW)

static __device__ inline f32x4 zero4() { f32x4 v = {0.f, 0.f, 0.f, 0.f}; return v; }

// ---------------- merged: x transpose (blocks 0..511) + PE tables / lwf (blocks 512..) ----------------
__global__ void k_prep(const float* __restrict__ x, f16* __restrict__ xT,
                       float* __restrict__ cy, float* __restrict__ cx,
                       f16* __restrict__ lwf, const float* __restrict__ lw)
{
    __shared__ float tile[64][65];
    const int bid = blockIdx.x;
    const int t = threadIdx.x;
    if (bid < 512) {
        const int b = bid >> 6;
        const int ct = (bid >> 2) & 15;
        const int nt = bid & 3;
        const int c0 = ct << 6, n0 = nt << 6;
        for (int i = 0; i < 16; i++) {
            int e = i * 256 + t;
            int cc = e >> 6, nn = e & 63;
            tile[cc][nn] = x[(size_t)((b << 10) + c0 + cc) * 256 + n0 + nn];
        }
        __syncthreads();
        for (int i = 0; i < 16; i++) {
            int e = i * 256 + t;
            int nn = e >> 6, cc = e & 63;
            xT[(size_t)((b << 8) + n0 + nn) * 1024 + c0 + cc] = (f16)tile[cc][nn];
        }
        return;
    }
    int id = (bid - 512) * 256 + t;
    const float r = 1.99999f / 256.f;
    if (id < 32768) {
        float* dst = (id < 16384) ? cy : cx;
        int e = id & 16383;
        int row = e >> 7, f = e & 127;
        float s = -0.99999f + r + 2.f * r * (float)row;
        float coef = 6.283185307179586f * powf(10.f, (float)(f & 63) * (1.f / 64.f));
        float arg = coef * s;
        dst[e] = (f < 64) ? cosf(arg) : sinf(arg);
    } else if (id < 33280) {
        // last1_w in B-fragment order: group id2 = c*64 + lane; lane = q4*16+nlo
        int id2 = id - 32768;
        int c = id2 >> 6, lane = id2 & 63;
        int nlo = lane & 15, q4 = lane >> 4;
        f16x8 v;
        #pragma unroll
        for (int ko = 0; ko < 8; ko++)
            v[ko] = (nlo < 3) ? (f16)(lw[nlo * 256 + (c << 5) + (q4 << 3) + ko] * SW_W) : (f16)0.f;
        *(f16x8*)(lwf + id2 * 8) = v;
    }
}

// ---------------- 64x64-tile MFMA GEMM ----------------
// MODE 0: x1 = conv_w @ x   (A=conv_w f32 *SW, B=xT f16, K=1024) -> x1 f16 (*SA1, +conv_b)
// MODE 1: W  = x1 @ wfine^T (A=x1 f16, B=wfine f32 *SW, K=256)   -> W f32 (+wfine_b)
template <int MODE>
__global__ __launch_bounds__(256, 4) void k_gemm(
    const float* __restrict__ Af32, const f16* __restrict__ Af16,
    const f16* __restrict__ Bf16, const float* __restrict__ Bf32,
    f16* __restrict__ out16, float* __restrict__ outW,
    const float* __restrict__ bias)
{
    constexpr int NC = MODE ? 8 : 32;
    __shared__ __align__(16) f16 Ab[2][64 * 32];
    __shared__ __align__(16) f16 Bb[2][64 * 32];
    const int t = threadIdx.x;
    const int lane = t & 63;
    const int wc = t >> 6;                 // wave = 16-col slice
    const int nlo = lane & 15, q4 = lane >> 4;
    const int blk = blockIdx.x;
    const int b = blk / 68;
    const int rem = blk % 68;
    const int m0 = (rem >> 2) << 6;
    const int n0 = (rem & 3) << 6;
    const int srow = t >> 2, sk = (t & 3) << 3;   // staged (row, k-offset)

    auto stageA = [&](int buf, int k0) {
        const int m = m0 + srow;
        f16x8 v;
        if (m < 1028) {
            if constexpr (MODE == 0) {
                const float* src = Af32 + (size_t)m * 1024 + k0 + sk;
                #pragma unroll
                for (int i = 0; i < 8; i++) v[i] = (f16)(src[i] * SW_W);
            } else {
                v = *(const f16x8*)(Af16 + (size_t)(b * 1028 + m) * 256 + k0 + sk);
            }
        } else {
            #pragma unroll
            for (int i = 0; i < 8; i++) v[i] = (f16)0.f;
        }
        *(f16x8*)(&Ab[buf][t << 3]) = v;
    };
    auto stageB = [&](int buf, int k0) {
        const int n = n0 + srow;
        f16x8 v;
        if constexpr (MODE == 0) {
            v = *(const f16x8*)(Bf16 + (size_t)((b << 8) + n) * 1024 + k0 + sk);
        } else {
            const float* src = Bf32 + (size_t)n * 256 + k0 + sk;
            #pragma unroll
            for (int i = 0; i < 8; i++) v[i] = (f16)(src[i] * SW_W);
        }
        *(f16x8*)(&Bb[buf][t << 3]) = v;
    };

    f32x4 acc[4];
    #pragma unroll
    for (int mt = 0; mt < 4; mt++) acc[mt] = zero4();

    stageA(0, 0); stageB(0, 0);
    __syncthreads();
    for (int c = 0; c < NC; c++) {
        const int cb = c & 1;
        if (c + 1 < NC) { stageA(cb ^ 1, (c + 1) << 5); stageB(cb ^ 1, (c + 1) << 5); }
        f16x8 af[4], bf;
        bf = *(const f16x8*)(&Bb[cb][(((wc << 4) + nlo) << 5) + (q4 << 3)]);
        #pragma unroll
        for (int mt = 0; mt < 4; mt++)
            af[mt] = *(const f16x8*)(&Ab[cb][(((mt << 4) + nlo) << 5) + (q4 << 3)]);
        #pragma unroll
        for (int mt = 0; mt < 4; mt++)
            acc[mt] = MFMA16(af[mt], bf, acc[mt]);
        __syncthreads();
    }
    const int nn = n0 + (wc << 4) + nlo;
    #pragma unroll
    for (int mt = 0; mt < 4; mt++) {
        #pragma unroll
        for (int i = 0; i < 4; i++) {
            const int m = m0 + (mt << 4) + (q4 << 2) + i;
            if (m < 1028) {
                if constexpr (MODE == 0) {
                    float v = (acc[mt][i] * INV_SW + bias[m]) * SA1_s;
                    out16[(size_t)(b * 1028 + m) * 256 + nn] = (f16)v;
                } else {
                    outW[(size_t)(b * 1028 + m) * 256 + nn] =
                        acc[mt][i] * INV_SA1SW + bias[nn];
                }
            }
        }
    }
}

// ---------------- merged: axby (blocks 0..255) + castw fragment-order (blocks 256..639) ----------------
__global__ void k_wprep(const float* __restrict__ cy, const float* __restrict__ cx,
                        const float* __restrict__ W, f16* __restrict__ ayF,
                        f16* __restrict__ bxF, f16* __restrict__ wjT)
{
    __shared__ float tile[64][65];
    const int bid = blockIdx.x;
    const int t = threadIdx.x;
    if (bid < 256) {
        const int b = bid >> 5, which = (bid >> 4) & 1, rtile = bid & 15;
        const int r0 = rtile << 3;
        const float* ctab = which ? cx : cy;
        const float* Wb = W + (size_t)(b * 1028 + (which ? 128 : 0)) * 256;
        float acc[8];
        #pragma unroll
        for (int r = 0; r < 8; r++) acc[r] = 0.f;
        for (int k = 0; k < 128; k++) {
            const float wv = Wb[(k << 8) + t];
            #pragma unroll
            for (int r = 0; r < 8; r++)
                acc[r] = fmaf(ctab[((r0 + r) << 7) + k], wv, acc[r]);
        }
        const float b1v = which ? 0.f : W[(size_t)(b * 1028 + 256) * 256 + t];
        f16* dst = which ? bxF : ayF;
        for (int r = 0; r < 8; r++)
            dst[(size_t)((b << 7) + r0 + r) * 256 + t] = (f16)((acc[r] + b1v) * SA_A);
        return;
    }
    // castw: write wj in MFMA B-fragment order:
    // element (n,k) -> dst[ ((c*4 + wc)*4 + nt)*512 + lane*8 + ko ],
    //   c=k>>5, q4=(k>>3)&3, ko=k&7, wc=n>>6, nt=(n>>4)&3, nlo=n&15, lane=q4*16+nlo
    const int id = bid - 256;                  // 384 = 8b * 3jj * 16 tiles
    const int b = id / 48;
    const int rr = id % 48;
    const int jj = rr / 16;
    const int tt = rr % 16;
    const int kt = tt >> 2, wt = tt & 3;       // k-tile (64k), wave-col tile (64n)
    const int k0 = kt << 6, n0 = wt << 6;
    const float* src = W + (size_t)(b * 1028 + 257 * (jj + 1)) * 256;
    for (int i = 0; i < 16; i++) {
        int e = i * 256 + t;
        int kk = e >> 6, nn = e & 63;
        tile[kk][nn] = src[(size_t)(k0 + kk) * 256 + n0 + nn];
    }
    __syncthreads();
    f16* dst = wjT + (size_t)(b * 3 + jj) * 65536;
    #pragma unroll
    for (int i = 0; i < 2; i++) {
        const int g = i * 256 + t;
        const int c_rel = g >> 8, sub = g & 255;
        const int nt = sub >> 6, ln = sub & 63;
        const int nl = ln & 15, q4g = ln >> 4;
        f16x8 v;
        #pragma unroll
        for (int ko = 0; ko < 8; ko++)
            v[ko] = (f16)(tile[(c_rel << 5) + (q4g << 3) + ko][(nt << 4) + nl] * SW_W);
        const int c = (kt << 1) + c_rel;
        *(f16x8*)(dst + (size_t)(((((c << 2) | wt) << 2) | nt) << 9) + (ln << 3)) = v;
    }
}

// ---------------- fused MLP: layers 2..4 + final projection + silu ----------------
// act: 64px x 256f f16 in LDS (slot-swizzled). Weights: direct fragment-ordered
// global loads (L2-resident, XCD-local via b=blk&7). Barriers: 2 per layer.
__global__ __launch_bounds__(256, 3) void k_main(
    const f16* __restrict__ wjT, const float* __restrict__ Wfull,
    const f16* __restrict__ ayF, const f16* __restrict__ bxF,
    const f16* __restrict__ lwf, const float* __restrict__ lb,
    const float* __restrict__ pa_p, float* __restrict__ out)
{
    __shared__ __align__(16) unsigned char actS[32768];     // 64 rows x 256 f16, slot-swizzled
    const int t = threadIdx.x;
    const int lane = t & 63;
    const int wc = t >> 6;                     // wave = 64-col slice
    const int nlo = lane & 15, q4 = lane >> 4;
    const int blk = blockIdx.x;
    const int b = blk & 7, rt = blk >> 3;      // batch = XCD index -> L2-local weights
    const int p0 = rt << 6;
    const int y = p0 >> 7, x0 = p0 & 127;
    const float pa = pa_p[0];

    // ---- init act = f16(prelu(ayF[y] + bxF[x])) ----
    {
        const int r = t & 63, g = t >> 6;
        const f16* ayr = ayF + (size_t)((b << 7) + y) * 256;
        const f16* bxr = bxF + (size_t)((b << 7) + x0 + r) * 256;
        const int rx = r & 7;
        #pragma unroll
        for (int mm = 0; mm < 8; mm++) {
            const int slot = (g << 3) + mm;
            const int f0 = slot << 3;
            f16x8 av = *(const f16x8*)(ayr + f0);
            f16x8 bv = *(const f16x8*)(bxr + f0);
            f16x8 v;
            #pragma unroll
            for (int i = 0; i < 8; i++) {
                float hv = (float)av[i] + (float)bv[i];
                hv = fmaxf(hv, 0.f) + pa * fminf(hv, 0.f);
                v[i] = (f16)hv;
            }
            *(f16x8*)(actS + (r << 9) + ((slot ^ rx) << 4)) = v;
        }
    }
    __syncthreads();

    for (int jj = 0; jj < 3; jj++) {
        const f16* wl = wjT + (size_t)(b * 3 + jj) * 65536;
        auto loadB = [&](f16x8* dstv, int c) {
            const f16* p = wl + (size_t)(((c << 2) | wc) << 11) + (lane << 3);
            #pragma unroll
            for (int nt = 0; nt < 4; nt++)
                dstv[nt] = *(const f16x8*)(p + (nt << 9));
        };
        f32x4 acc[4][4];
        #pragma unroll
        for (int pt = 0; pt < 4; pt++)
            #pragma unroll
            for (int nt = 0; nt < 4; nt++) acc[pt][nt] = zero4();

        f16x8 bfA[4], bfB[4];
        loadB(bfA, 0);
        #pragma unroll
        for (int c = 0; c < 8; c++) {
            f16x8* cur = (c & 1) ? bfB : bfA;
            f16x8* nxt = (c & 1) ? bfA : bfB;
            if (c < 7) loadB(nxt, c + 1);
            const int sl = (c << 2) + q4;
            f16x8 af[4];
            #pragma unroll
            for (int pt = 0; pt < 4; pt++) {
                const int rr = (pt << 4) + nlo;
                af[pt] = *(const f16x8*)(actS + (rr << 9) + ((sl ^ (rr & 7)) << 4));
            }
            // swapped operands: D rows = weight n, cols = pixel ->
            // lane holds pixel = pt*16+nlo, n = wc*64 + nt*16 + q4*4 + i (consecutive i!)
            #pragma unroll
            for (int pt = 0; pt < 4; pt++)
                #pragma unroll
                for (int nt = 0; nt < 4; nt++)
                    acc[pt][nt] = MFMA16(cur[nt], af[pt], acc[pt][nt]);
        }
        __syncthreads();   // all reads of actS done

        // epilogue: act <- f16(prelu(acc/SW + SA*b_j)); 8B packed writes
        const float* bias = Wfull + (size_t)(b * 1028 + 257 * (jj + 1) + 256) * 256;
        #pragma unroll
        for (int nt = 0; nt < 4; nt++) {
            const int nb = (wc << 6) + (nt << 4) + (q4 << 2);   // first of 4 consecutive n
            const f32x4 b4 = *(const f32x4*)(bias + nb);
            #pragma unroll
            for (int pt = 0; pt < 4; pt++) {
                const int rr = (pt << 4) + nlo;
                f16x4 pk;
                #pragma unroll
                for (int i = 0; i < 4; i++) {
                    float v = acc[pt][nt][i] * INV_SW + b4[i] * SA_A;
                    v = fmaxf(v, 0.f) + pa * fminf(v, 0.f);
                    pk[i] = (f16)v;
                }
                *(f16x4*)(actS + (rr << 9) + (((nb >> 3) ^ (rr & 7)) << 4) + ((nb & 7) << 1)) = pk;
            }
        }
        __syncthreads();   // next layer / projection reads other waves' columns
    }

    // ---- final 256->3 projection + silu: each wave owns one 16-px tile ----
    {
        f32x4 acc2 = zero4();
        const int rr = (wc << 4) + nlo;
        #pragma unroll
        for (int c = 0; c < 8; c++) {
            const int sl = (c << 2) + q4;
            const f16x8 af = *(const f16x8*)(actS + (rr << 9) + ((sl ^ (rr & 7)) << 4));
            const f16x8 lf = *(const f16x8*)(lwf + (((c << 6) + lane) << 3));
            acc2 = MFMA16(af, lf, acc2);
        }
        if (nlo < 3) {
            const float lbv = lb[nlo];
            float* ob = out + ((size_t)(b * 3 + nlo) << 14) + p0 + (wc << 4) + (q4 << 2);
            #pragma unroll
            for (int i = 0; i < 4; i++) {
                float z = acc2[i] * INV_SASW + lbv;
                ob[i] = z / (1.f + expf(-z));
            }
        }
    }
}

extern "C" void kernel_launch(void* const* d_in, const int* in_sizes, int n_in,
                              void* d_out, int out_size, void* d_ws, size_t ws_size,
                              hipStream_t stream)
{
    (void)in_sizes; (void)n_in; (void)out_size; (void)ws_size;
    const float* x       = (const float*)d_in[0];
    const float* conv_w  = (const float*)d_in[1];
    const float* conv_b  = (const float*)d_in[2];
    const float* wfine_w = (const float*)d_in[3];
    const float* wfine_b = (const float*)d_in[4];
    const float* last1_w = (const float*)d_in[5];
    const float* last1_b = (const float*)d_in[6];
    const float* prelu_a = (const float*)d_in[7];
    char* ws = (char*)d_ws;
    float* Cy  = (float*)(ws + OFF_CY);
    float* Cx  = (float*)(ws + OFF_CX);
    f16*   lwf = (f16*)(ws + OFF_LW);
    f16*   xT  = (f16*)(ws + OFF_XT);
    f16*   x1  = (f16*)(ws + OFF_X1);
    float* W   = (float*)(ws + OFF_W);
    f16*   AyF = (f16*)(ws + OFF_AY);
    f16*   BxF = (f16*)(ws + OFF_BX);
    f16*   wjT = (f16*)(ws + OFF_WT);

    k_prep<<<642, 256, 0, stream>>>(x, xT, Cy, Cx, lwf, last1_w);
    k_gemm<0><<<544, 256, 0, stream>>>(conv_w, nullptr, xT, nullptr, x1, nullptr, conv_b);
    k_gemm<1><<<544, 256, 0, stream>>>(nullptr, x1, nullptr, wfine_w, nullptr, W, wfine_b);
    k_wprep<<<640, 256, 0, stream>>>(Cy, Cx, W, AyF, BxF, wjT);
    k_main<<<2048, 256, 0, stream>>>(wjT, W, AyF, BxF, lwf, last1_b, prelu_a, (float*)d_out);
}

// Round 6
// 114.238 us; speedup vs baseline: 2.2917x; 1.0868x over previous
//
#include <hip/hip_runtime.h>
#include <hip/hip_fp16.h>
#include <math.h>

typedef _Float16 f16;
typedef _Float16 f16x4 __attribute__((ext_vector_type(4)));
typedef _Float16 f16x8 __attribute__((ext_vector_type(8)));
typedef float f32x4 __attribute__((ext_vector_type(4)));

#define MFMA16(a, b, c) __builtin_amdgcn_mfma_f32_16x16x32_f16((a), (b), (c), 0, 0, 0)

static constexpr float SW_W   = 1024.f;
static constexpr float SA_A   = 64.f;
static constexpr float SA1_s  = 16.f;
static constexpr float INV_SW    = 1.f / 1024.f;
static constexpr float INV_SASW  = 1.f / (64.f * 1024.f);
static constexpr float INV_SA1SW = 1.f / (16.f * 1024.f);

// workspace layout (bytes)
static constexpr size_t OFF_CY = 0;                                   // 128*128 f32
static constexpr size_t OFF_CX = OFF_CY + 128 * 128 * 4;
static constexpr size_t OFF_LW = OFF_CX + 128 * 128 * 4;              // 512*8 f16 frag-ordered last1_w*SW
static constexpr size_t OFF_XT = OFF_LW + 16 * 256 * 2;               // 8*256*1024 f16  x transposed
static constexpr size_t OFF_CW = OFF_XT + (size_t)8 * 256 * 1024 * 2; // 1088*1024 f16 conv_w*SW (padded)
static constexpr size_t OFF_WF = OFF_CW + (size_t)1088 * 1024 * 2;    // 256*256 f16 frag-ordered wfine*SW
static constexpr size_t OFF_W  = OFF_WF + 256 * 256 * 2;              // 8*1028*256 f32
static constexpr size_t OFF_AY = OFF_W  + (size_t)8 * 1028 * 256 * 4; // 8*128*256 f16
static constexpr size_t OFF_BX = OFF_AY + (size_t)8 * 128 * 256 * 2;  // 8*128*256 f16
static constexpr size_t OFF_WT = OFF_BX + (size_t)8 * 128 * 256 * 2;  // 8*3*65536 f16 frag-ordered wj*SW

static __device__ inline f32x4 zero4() { f32x4 v = {0.f, 0.f, 0.f, 0.f}; return v; }

// ---- k_prep: x transpose | PE tables + lwf | conv_w cast | wfine frag-cast ----
__global__ void k_prep(const float* __restrict__ x, f16* __restrict__ xT,
                       float* __restrict__ cy, float* __restrict__ cx,
                       f16* __restrict__ lwf, const float* __restrict__ lw,
                       const float* __restrict__ cw, f16* __restrict__ cw16,
                       const float* __restrict__ wf, f16* __restrict__ wf16)
{
    __shared__ float tile[64][65];
    const int bid = blockIdx.x;
    const int t = threadIdx.x;
    if (bid < 512) {
        const int b = bid >> 6;
        const int ct = (bid >> 2) & 15;
        const int nt = bid & 3;
        const int c0 = ct << 6, n0 = nt << 6;
        for (int i = 0; i < 16; i++) {
            int e = i * 256 + t;
            int cc = e >> 6, nn = e & 63;
            tile[cc][nn] = x[(size_t)((b << 10) + c0 + cc) * 256 + n0 + nn];
        }
        __syncthreads();
        for (int i = 0; i < 16; i++) {
            int e = i * 256 + t;
            int nn = e >> 6, cc = e & 63;
            xT[(size_t)((b << 8) + n0 + nn) * 1024 + c0 + cc] = (f16)tile[cc][nn];
        }
        return;
    }
    if (bid < 642) {
        int id = (bid - 512) * 256 + t;
        const float r = 1.99999f / 256.f;
        if (id < 32768) {
            float* dst = (id < 16384) ? cy : cx;
            int e = id & 16383;
            int row = e >> 7, f = e & 127;
            float s = -0.99999f + r + 2.f * r * (float)row;
            float coef = 6.283185307179586f * powf(10.f, (float)(f & 63) * (1.f / 64.f));
            float arg = coef * s;
            dst[e] = (f < 64) ? cosf(arg) : sinf(arg);
        } else if (id < 33280) {
            int id2 = id - 32768;
            int c = id2 >> 6, lane = id2 & 63;
            int nlo = lane & 15, q4 = lane >> 4;
            f16x8 v;
            #pragma unroll
            for (int ko = 0; ko < 8; ko++)
                v[ko] = (nlo < 3) ? (f16)(lw[nlo * 256 + (c << 5) + (q4 << 3) + ko] * SW_W) : (f16)0.f;
            *(f16x8*)(lwf + id2 * 8) = v;
        }
        return;
    }
    if (bid < 1186) {
        // conv_w (1028x1024 f32) -> cw16 (1088x1024 f16 *SW, zero-padded rows)
        const int g8 = (bid - 642) * 256 + t;
        const int row = g8 >> 7, col0 = (g8 & 127) << 3;
        f16x8 v;
        if (row < 1028) {
            const float* src = cw + (size_t)row * 1024 + col0;
            #pragma unroll
            for (int i = 0; i < 8; i++) v[i] = (f16)(src[i] * SW_W);
        } else {
            #pragma unroll
            for (int i = 0; i < 8; i++) v[i] = (f16)0.f;
        }
        *(f16x8*)(cw16 + (size_t)g8 * 8) = v;
        return;
    }
    {
        // wfine (256x256) -> B-fragment order f16 *SW
        const int gg = (bid - 1186) * 256 + t;      // 0..8191
        const int lane = gg & 63, nt = (gg >> 6) & 3, wt = (gg >> 8) & 3, c = gg >> 10;
        const int nlo = lane & 15, q4 = lane >> 4;
        const int n = (wt << 6) + (nt << 4) + nlo;
        f16x8 v;
        #pragma unroll
        for (int ko = 0; ko < 8; ko++)
            v[ko] = (f16)(wf[(size_t)n * 256 + (c << 5) + (q4 << 3) + ko] * SW_W);
        *(f16x8*)(wf16 + (size_t)gg * 8) = v;
    }
}

// ---- fused conv-GEMM + W-GEMM: one block = 64 W-rows x (all 256 px) ----
// stage 1: x1_tile[64r x 256p] = cw16[m0..m0+63] @ xT(b)   (K=1024, LDS-staged)
// stage 2: W[m0..][256j]       = x1_tile @ wfineT          (K=256, x1 in LDS, wf16 frag-direct)
__global__ __launch_bounds__(256, 2) void k_fused(
    const f16* __restrict__ cw16, const f16* __restrict__ xT,
    const f16* __restrict__ wf16, const float* __restrict__ conv_b,
    const float* __restrict__ wfine_b, float* __restrict__ W)
{
    __shared__ __align__(16) f16 Ab[2][64 * 32];
    __shared__ __align__(16) f16 Bb[2][256 * 32];
    __shared__ __align__(16) unsigned char x1S[32768];  // 64r x 256p f16, slot-swizzled
    const int t = threadIdx.x;
    const int lane = t & 63;
    const int wc = t >> 6;
    const int nlo = lane & 15, q4 = lane >> 4;
    const int b = blockIdx.x & 7, mtile = blockIdx.x >> 3;   // 136 blocks
    const int m0 = mtile << 6;

    auto stageA = [&](int buf, int k0) {
        *(f16x8*)(&Ab[buf][t << 3]) =
            *(const f16x8*)(cw16 + (size_t)(m0 + (t >> 2)) * 1024 + k0 + ((t & 3) << 3));
    };
    auto stageB = [&](int buf, int k0) {
        #pragma unroll
        for (int i = 0; i < 4; i++)
            *(f16x8*)(&Bb[buf][(i * 256 + t) << 3]) =
                *(const f16x8*)(xT + (size_t)((b << 8) + (i << 6) + (t >> 2)) * 1024 + k0 + ((t & 3) << 3));
    };

    f32x4 acc1[4][4];
    #pragma unroll
    for (int pt = 0; pt < 4; pt++)
        #pragma unroll
        for (int mc = 0; mc < 4; mc++) acc1[pt][mc] = zero4();

    stageA(0, 0); stageB(0, 0);
    __syncthreads();
    for (int c = 0; c < 32; c++) {
        const int cb = c & 1;
        if (c + 1 < 32) { stageA(cb ^ 1, (c + 1) << 5); stageB(cb ^ 1, (c + 1) << 5); }
        f16x8 bf[4], af[4];
        #pragma unroll
        for (int pt = 0; pt < 4; pt++)
            bf[pt] = *(const f16x8*)(&Bb[cb][((wc << 8) + (((pt << 4) + nlo) << 2) + q4) << 3]);
        #pragma unroll
        for (int mc = 0; mc < 4; mc++)
            af[mc] = *(const f16x8*)(&Ab[cb][(((((mc << 4) + nlo) << 2) + q4)) << 3]);
        #pragma unroll
        for (int pt = 0; pt < 4; pt++)
            #pragma unroll
            for (int mc = 0; mc < 4; mc++)
                acc1[pt][mc] = MFMA16(bf[pt], af[mc], acc1[pt][mc]);
        __syncthreads();
    }

    // epilogue 1: x1S[r][p] = f16(SA1*(acc/SW + conv_b))   (r = m-local via nlo, p via q4,i)
    {
        float cbv[4];
        #pragma unroll
        for (int mc = 0; mc < 4; mc++) {
            const int m = m0 + (mc << 4) + nlo;
            cbv[mc] = (m < 1028) ? conv_b[m] : 0.f;
        }
        #pragma unroll
        for (int pt = 0; pt < 4; pt++) {
            const int p0 = (wc << 6) + (pt << 4) + (q4 << 2);
            #pragma unroll
            for (int mc = 0; mc < 4; mc++) {
                const int r = (mc << 4) + nlo;
                f16x4 pk;
                #pragma unroll
                for (int i = 0; i < 4; i++)
                    pk[i] = (f16)((acc1[pt][mc][i] * INV_SW + cbv[mc]) * SA1_s);
                *(f16x4*)(x1S + (r << 9) + (((p0 >> 3) ^ (r & 7)) << 4) + ((p0 & 7) << 1)) = pk;
            }
        }
    }
    __syncthreads();

    // stage 2: W rows m0.., all 256 j; K = 256 px in 8 chunks
    f32x4 acc2[4][4];
    #pragma unroll
    for (int mc = 0; mc < 4; mc++)
        #pragma unroll
        for (int jt = 0; jt < 4; jt++) acc2[mc][jt] = zero4();

    auto loadW = [&](f16x8* d, int c2) {
        const f16* p = wf16 + (size_t)((((c2 << 2) | wc)) << 11) + (lane << 3);
        #pragma unroll
        for (int jt = 0; jt < 4; jt++) d[jt] = *(const f16x8*)(p + (jt << 9));
    };
    f16x8 wfA[4], wfB[4];
    loadW(wfA, 0);
    #pragma unroll
    for (int c2 = 0; c2 < 8; c2++) {
        f16x8* cur = (c2 & 1) ? wfB : wfA;
        f16x8* nxt = (c2 & 1) ? wfA : wfB;
        if (c2 < 7) loadW(nxt, c2 + 1);
        f16x8 af2[4];
        #pragma unroll
        for (int mc = 0; mc < 4; mc++) {
            const int r = (mc << 4) + nlo;
            af2[mc] = *(const f16x8*)(x1S + (r << 9) + ((((c2 << 2) + q4) ^ (r & 7)) << 4));
        }
        #pragma unroll
        for (int mc = 0; mc < 4; mc++)
            #pragma unroll
            for (int jt = 0; jt < 4; jt++)
                acc2[mc][jt] = MFMA16(cur[jt], af2[mc], acc2[mc][jt]);
    }
    #pragma unroll
    for (int jt = 0; jt < 4; jt++) {
        const int j0 = (wc << 6) + (jt << 4) + (q4 << 2);
        const f32x4 b4 = *(const f32x4*)(wfine_b + j0);
        #pragma unroll
        for (int mc = 0; mc < 4; mc++) {
            const int m = m0 + (mc << 4) + nlo;
            if (m < 1028) {
                f32x4 o;
                #pragma unroll
                for (int i = 0; i < 4; i++) o[i] = acc2[mc][jt][i] * INV_SA1SW + b4[i];
                *(f32x4*)(W + ((size_t)(b * 1028 + m) << 8) + j0) = o;
            }
        }
    }
}

// ---- merged: axby (blocks 0..255) + castw fragment-order (blocks 256..639) ----
__global__ void k_wprep(const float* __restrict__ cy, const float* __restrict__ cx,
                        const float* __restrict__ W, f16* __restrict__ ayF,
                        f16* __restrict__ bxF, f16* __restrict__ wjT)
{
    __shared__ float tile[64][65];
    const int bid = blockIdx.x;
    const int t = threadIdx.x;
    if (bid < 256) {
        const int b = bid >> 5, which = (bid >> 4) & 1, rtile = bid & 15;
        const int r0 = rtile << 3;
        const float* ctab = which ? cx : cy;
        const float* Wb = W + (size_t)(b * 1028 + (which ? 128 : 0)) * 256;
        float acc[8];
        #pragma unroll
        for (int r = 0; r < 8; r++) acc[r] = 0.f;
        for (int k = 0; k < 128; k++) {
            const float wv = Wb[(k << 8) + t];
            #pragma unroll
            for (int r = 0; r < 8; r++)
                acc[r] = fmaf(ctab[((r0 + r) << 7) + k], wv, acc[r]);
        }
        const float b1v = which ? 0.f : W[(size_t)(b * 1028 + 256) * 256 + t];
        f16* dst = which ? bxF : ayF;
        for (int r = 0; r < 8; r++)
            dst[(size_t)((b << 7) + r0 + r) * 256 + t] = (f16)((acc[r] + b1v) * SA_A);
        return;
    }
    const int id = bid - 256;                  // 384 = 8b * 3jj * 16 tiles
    const int b = id / 48;
    const int rr = id % 48;
    const int jj = rr / 16;
    const int tt = rr % 16;
    const int kt = tt >> 2, wt = tt & 3;
    const int k0 = kt << 6, n0 = wt << 6;
    const float* src = W + (size_t)(b * 1028 + 257 * (jj + 1)) * 256;
    for (int i = 0; i < 16; i++) {
        int e = i * 256 + t;
        int kk = e >> 6, nn = e & 63;
        tile[kk][nn] = src[(size_t)(k0 + kk) * 256 + n0 + nn];
    }
    __syncthreads();
    f16* dst = wjT + (size_t)(b * 3 + jj) * 65536;
    #pragma unroll
    for (int i = 0; i < 2; i++) {
        const int g = i * 256 + t;
        const int c_rel = g >> 8, sub = g & 255;
        const int nt = sub >> 6, ln = sub & 63;
        const int nl = ln & 15, q4g = ln >> 4;
        f16x8 v;
        #pragma unroll
        for (int ko = 0; ko < 8; ko++)
            v[ko] = (f16)(tile[(c_rel << 5) + (q4g << 3) + ko][(nt << 4) + nl] * SW_W);
        const int c = (kt << 1) + c_rel;
        *(f16x8*)(dst + (size_t)(((((c << 2) | wt) << 2) | nt) << 9) + (ln << 3)) = v;
    }
}

// ---- fused MLP: layers 2..4 + final projection + silu ----
__global__ __launch_bounds__(256, 3) void k_main(
    const f16* __restrict__ wjT, const float* __restrict__ Wfull,
    const f16* __restrict__ ayF, const f16* __restrict__ bxF,
    const f16* __restrict__ lwf, const float* __restrict__ lb,
    const float* __restrict__ pa_p, float* __restrict__ out)
{
    __shared__ __align__(16) unsigned char actS[32768];     // 64px x 256f f16, slot-swizzled
    const int t = threadIdx.x;
    const int lane = t & 63;
    const int wc = t >> 6;
    const int nlo = lane & 15, q4 = lane >> 4;
    const int blk = blockIdx.x;
    const int b = blk & 7, rt = blk >> 3;      // batch = XCD index -> L2-local weights
    const int p0 = rt << 6;
    const int y = p0 >> 7, x0 = p0 & 127;
    const float pa = pa_p[0];

    const f16* wl0 = wjT + (size_t)(b * 3) * 65536;
    // g = global chunk 0..23 (layer g>>3, k-chunk g&7)
    auto loadBg = [&](f16x8* dstv, int g) {
        const f16* p = wl0 + (size_t)(g >> 3) * 65536 + ((size_t)((((g & 7) << 2) | wc)) << 11) + (lane << 3);
        #pragma unroll
        for (int nt = 0; nt < 4; nt++) dstv[nt] = *(const f16x8*)(p + (nt << 9));
    };

    f16x8 bfA[4], bfB[4];
    loadBg(bfA, 0);          // persistent cross-layer double-buffer

    // ---- init act = f16(prelu(ayF[y] + bxF[x])) ----
    {
        const int r = t & 63, g = t >> 6;
        const f16* ayr = ayF + (size_t)((b << 7) + y) * 256;
        const f16* bxr = bxF + (size_t)((b << 7) + x0 + r) * 256;
        const int rx = r & 7;
        #pragma unroll
        for (int mm = 0; mm < 8; mm++) {
            const int slot = (g << 3) + mm;
            const int f0 = slot << 3;
            f16x8 av = *(const f16x8*)(ayr + f0);
            f16x8 bv = *(const f16x8*)(bxr + f0);
            f16x8 v;
            #pragma unroll
            for (int i = 0; i < 8; i++) {
                float hv = (float)av[i] + (float)bv[i];
                hv = fmaxf(hv, 0.f) + pa * fminf(hv, 0.f);
                v[i] = (f16)hv;
            }
            *(f16x8*)(actS + (r << 9) + ((slot ^ rx) << 4)) = v;
        }
    }
    __syncthreads();

    for (int jj = 0; jj < 3; jj++) {
        // bias prefetch at layer top (hidden under chunk loop)
        const float* bias = Wfull + (size_t)(b * 1028 + 257 * (jj + 1) + 256) * 256;
        f32x4 bias4[4];
        #pragma unroll
        for (int nt = 0; nt < 4; nt++)
            bias4[nt] = *(const f32x4*)(bias + (wc << 6) + (nt << 4) + (q4 << 2));

        f32x4 acc[4][4];
        #pragma unroll
        for (int pt = 0; pt < 4; pt++)
            #pragma unroll
            for (int nt = 0; nt < 4; nt++) acc[pt][nt] = zero4();

        #pragma unroll
        for (int c = 0; c < 8; c++) {
            const int g = jj * 8 + c;
            f16x8* cur = (g & 1) ? bfB : bfA;
            f16x8* nxt = (g & 1) ? bfA : bfB;
            if (g < 23) loadBg(nxt, g + 1);    // crosses layer boundary at c==7
            const int sl = (c << 2) + q4;
            f16x8 af[4];
            #pragma unroll
            for (int pt = 0; pt < 4; pt++) {
                const int rr = (pt << 4) + nlo;
                af[pt] = *(const f16x8*)(actS + (rr << 9) + ((sl ^ (rr & 7)) << 4));
            }
            #pragma unroll
            for (int pt = 0; pt < 4; pt++)
                #pragma unroll
                for (int nt = 0; nt < 4; nt++)
                    acc[pt][nt] = MFMA16(cur[nt], af[pt], acc[pt][nt]);
        }
        __syncthreads();   // all reads of actS done

        // epilogue: act <- f16(prelu(acc/SW + SA*b_j)); 8B packed writes
        #pragma unroll
        for (int nt = 0; nt < 4; nt++) {
            const int nb = (wc << 6) + (nt << 4) + (q4 << 2);
            #pragma unroll
            for (int pt = 0; pt < 4; pt++) {
                const int rr = (pt << 4) + nlo;
                f16x4 pk;
                #pragma unroll
                for (int i = 0; i < 4; i++) {
                    float v = acc[pt][nt][i] * INV_SW + bias4[nt][i] * SA_A;
                    v = fmaxf(v, 0.f) + pa * fminf(v, 0.f);
                    pk[i] = (f16)v;
                }
                *(f16x4*)(actS + (rr << 9) + (((nb >> 3) ^ (rr & 7)) << 4) + ((nb & 7) << 1)) = pk;
            }
        }
        __syncthreads();
    }

    // ---- final 256->3 projection + silu: each wave owns one 16-px tile ----
    {
        f32x4 acc2 = zero4();
        const int rr = (wc << 4) + nlo;
        #pragma unroll
        for (int c = 0; c < 8; c++) {
            const int sl = (c << 2) + q4;
            const f16x8 af = *(const f16x8*)(actS + (rr << 9) + ((sl ^ (rr & 7)) << 4));
            const f16x8 lf = *(const f16x8*)(lwf + (((c << 6) + lane) << 3));
            acc2 = MFMA16(af, lf, acc2);
        }
        if (nlo < 3) {
            const float lbv = lb[nlo];
            float* ob = out + ((size_t)(b * 3 + nlo) << 14) + p0 + (wc << 4) + (q4 << 2);
            #pragma unroll
            for (int i = 0; i < 4; i++) {
                float z = acc2[i] * INV_SASW + lbv;
                ob[i] = z / (1.f + expf(-z));
            }
        }
    }
}

extern "C" void kernel_launch(void* const* d_in, const int* in_sizes, int n_in,
                              void* d_out, int out_size, void* d_ws, size_t ws_size,
                              hipStream_t stream)
{
    (void)in_sizes; (void)n_in; (void)out_size; (void)ws_size;
    const float* x       = (const float*)d_in[0];
    const float* conv_w  = (const float*)d_in[1];
    const float* conv_b  = (const float*)d_in[2];
    const float* wfine_w = (const float*)d_in[3];
    const float* wfine_b = (const float*)d_in[4];
    const float* last1_w = (const float*)d_in[5];
    const float* last1_b = (const float*)d_in[6];
    const float* prelu_a = (const float*)d_in[7];
    char* ws = (char*)d_ws;
    float* Cy  = (float*)(ws + OFF_CY);
    float* Cx  = (float*)(ws + OFF_CX);
    f16*   lwf = (f16*)(ws + OFF_LW);
    f16*   xT  = (f16*)(ws + OFF_XT);
    f16*   cw16= (f16*)(ws + OFF_CW);
    f16*   wf16= (f16*)(ws + OFF_WF);
    float* W   = (float*)(ws + OFF_W);
    f16*   AyF = (f16*)(ws + OFF_AY);
    f16*   BxF = (f16*)(ws + OFF_BX);
    f16*   wjT = (f16*)(ws + OFF_WT);

    k_prep<<<1218, 256, 0, stream>>>(x, xT, Cy, Cx, lwf, last1_w, conv_w, cw16, wfine_w, wf16);
    k_fused<<<136, 256, 0, stream>>>(cw16, xT, wf16, conv_b, wfine_b, W);
    k_wprep<<<640, 256, 0, stream>>>(Cy, Cx, W, AyF, BxF, wjT);
    k_main<<<2048, 256, 0, stream>>>(wjT, W, AyF, BxF, lwf, last1_b, prelu_a, (float*)d_out);
}